// Round 4
// baseline (938.250 us; speedup 1.0000x reference)
//
#include <hip/hip_runtime.h>
#include <hip/hip_bf16.h>
#include <math.h>

#define BSZ 8
#define NLVL 4
#define E 512
#define H 8
#define D 64
#define FFN 2048
#define NNZ 131072
#define NQ 32
#define P32 32
#define NEGF -3.0e38f

typedef __attribute__((ext_vector_type(8))) short bf16x8;
typedef __attribute__((ext_vector_type(4))) float f32x4;

// ws layout (float offsets). ints counts_b[8], off_b[8] at front.
#define WS_QROT   16
#define WS_WSUM   (WS_QROT + NQ*E)
#define WS_OATT   (WS_WSUM + BSZ*P32*E)
#define WS_O2     (WS_OATT + NQ*E)
#define WS_Y      (WS_O2 + NQ*E)
#define WS_HID    (WS_Y + NQ*E)
#define WS_PART   (WS_HID + NQ*FFN)          // [512 chunks][32 p][512 e] f32 (wkt lives here pre-flash)
#define WS_ML     (WS_PART + 512*P32*E)      // [512][32][2] f32
#define WS_WALL   (WS_ML + 512*P32*2)        // bf16 [b][128][512] (shorts)

__device__ inline short f2bf(float x) {
    __hip_bfloat16 h = __float2bfloat16(x);
    union { __hip_bfloat16 v; short s; } u; u.v = h; return u.s;
}

// ================= k_pretr: fused {hist+offsets} and {Wkv K-part transpose} =================
// grid 65 x 1024 thr. blocks 0..63: transpose tile. block 64: histogram + offsets.
__global__ __launch_bounds__(1024) void k_pretr(const float* __restrict__ Wkv,
                                                float* __restrict__ wkt,
                                                const int* __restrict__ fb,
                                                int* __restrict__ wsi) {
    __shared__ float tile[64][65];
    int t = threadIdx.x;
    if (blockIdx.x < 64) {
        if (t < 256) {
            int ct = blockIdx.x & 7, et = blockIdx.x >> 3;
            int tc = t & 63, tr = t >> 6;
#pragma unroll
            for (int i = 0; i < 16; i++) {
                int e = et * 64 + tr + i * 4;
                tile[tr + i * 4][tc] = Wkv[(size_t)e * (2 * E) + ct * 64 + tc];
            }
        }
        __syncthreads();
        if (t < 256) {
            int ct = blockIdx.x & 7, et = blockIdx.x >> 3;
            int tc = t & 63, tr = t >> 6;
#pragma unroll
            for (int i = 0; i < 16; i++) {
                int c = tr + i * 4;
                wkt[(size_t)(ct * 64 + c) * E + et * 64 + tc] = tile[tc][c];
            }
        }
        return;
    }
    // histogram: per-thread register counters, no atomics
    int c[8];
#pragma unroll
    for (int q = 0; q < 8; q++) c[q] = 0;
    for (int j = t; j < NNZ; j += 1024) {
        int v = fb[j];
#pragma unroll
        for (int q = 0; q < 8; q++) c[q] += (v == q) ? 1 : 0;
    }
    // wave reduce each counter
#pragma unroll
    for (int q = 0; q < 8; q++)
        for (int o = 32; o > 0; o >>= 1) c[q] += __shfl_down(c[q], o, 64);
    __shared__ int hs[16][8];
    int w = t >> 6;
    if ((t & 63) == 0) {
#pragma unroll
        for (int q = 0; q < 8; q++) hs[w][q] = c[q];
    }
    __syncthreads();
    if (t == 0) {
        int tot[8];
#pragma unroll
        for (int q = 0; q < 8; q++) {
            int s = 0;
            for (int ww = 0; ww < 16; ww++) s += hs[ww][q];
            tot[q] = s;
        }
        int run = 0;
        for (int b = 0; b < 8; b++) {
            wsi[b] = tot[b];
            wsi[8 + b] = run;
            run += tot[b];
        }
    }
}

// ================= k_qw: fused {q = rope(LN(bg)@Wq)} + {Wall build} =================
// grid 32 (one block per q-row r), 256 thr. q never leaves LDS.
__global__ __launch_bounds__(256) void k_qw(const float* __restrict__ bg,
                                            const float* __restrict__ Wq,
                                            const float* __restrict__ wkt,
                                            const float* __restrict__ rf,
                                            const float* __restrict__ g,
                                            const float* __restrict__ bb,
                                            short* __restrict__ wall) {
    __shared__ float xr[E];
    __shared__ float qrow[E];
    __shared__ float qrot[E];
    __shared__ float ubuf[32 * 64];   // [combo = h*4+lvl][64]
    __shared__ float red[8];
    int r = blockIdx.x, t = threadIdx.x;
    // ---- LN ----
    float v0 = bg[r * E + t], v1 = bg[r * E + t + 256];
    float s = v0 + v1;
    for (int o = 32; o > 0; o >>= 1) s += __shfl_down(s, o, 64);
    if ((t & 63) == 0) red[t >> 6] = s;
    __syncthreads();
    if (t == 0) red[0] = (red[0] + red[1] + red[2] + red[3]) * (1.0f / E);
    __syncthreads();
    float mu = red[0];
    __syncthreads();
    float d0 = v0 - mu, d1 = v1 - mu;
    s = d0 * d0 + d1 * d1;
    for (int o = 32; o > 0; o >>= 1) s += __shfl_down(s, o, 64);
    if ((t & 63) == 0) red[t >> 6] = s;
    __syncthreads();
    if (t == 0) red[0] = rsqrtf((red[0] + red[1] + red[2] + red[3]) * (1.0f / E) + 1e-5f);
    __syncthreads();
    float rstd = red[0];
    xr[t] = d0 * rstd * g[t] + bb[t];
    xr[t + 256] = d1 * rstd * g[t + 256] + bb[t + 256];
    __syncthreads();
    // ---- q = xr @ Wq ----
    for (int half = 0; half < 2; half++) {
        int cc = t + half * 256;
        float acc = 0.f;
        for (int e = 0; e < E; e++) acc += xr[e] * Wq[e * E + cc];
        qrow[cc] = acc;
    }
    __syncthreads();
    // ---- rope by q-level ----
    {
        int c0 = 2 * t, c1 = c0 + 1;
        int h = c0 >> 6, ii = (c0 & 63) >> 1;
        float freq = rf[h * 32 + ii];
        float pos = (float)(r >> 3);
        float a = pos * freq, ca = cosf(a), sa = sinf(a);
        float x1 = qrow[c0], x2 = qrow[c1];
        qrot[c0] = x1 * ca - x2 * sa;
        qrot[c1] = x1 * sa + x2 * ca;
    }
    __syncthreads();
    // ---- all 32 (h,lvl) rotated-u vectors ----
#pragma unroll
    for (int i = 0; i < 4; i++) {
        int tk = i * 256 + t;        // 1024 tasks = 32 combos x 32 pairs
        int combo = tk >> 5, pr = tk & 31;
        int h = combo >> 2, lvl = combo & 3;
        float freq = rf[h * 32 + pr];
        float a = (float)lvl * freq;
        float ca = cosf(a), sa = sinf(a);
        float x1 = qrot[h * D + 2 * pr], x2 = qrot[h * D + 2 * pr + 1];
        ubuf[combo * 64 + 2 * pr] = x1 * ca + x2 * sa;
        ubuf[combo * 64 + 2 * pr + 1] = -x1 * sa + x2 * ca;
    }
    __syncthreads();
    // ---- wall rows: wall[b][lvl*32+l*8+h][e] = 0.125 * (u . WkT[h*64+ :, e]) ----
    int b = r >> 2, l = r & 3;
    for (int combo = 0; combo < 32; combo++) {
        int h = combo >> 2, lvl = combo & 3;
        const float* wt = wkt + (size_t)(h * D) * E;
        float acc0 = 0.f, acc1 = 0.f;
#pragma unroll
        for (int c = 0; c < D; c++) {
            float uc = ubuf[combo * 64 + c];
            acc0 += wt[(size_t)c * E + t] * uc;
            acc1 += wt[(size_t)c * E + t + 256] * uc;
        }
        int n = lvl * 32 + l * 8 + h;
        short* o = wall + ((size_t)(b * 128 + n)) * E;
        o[t] = f2bf(acc0 * 0.125f);
        o[t + 256] = f2bf(acc1 * 0.125f);
    }
}

// ================= k_flash: round-0 body verbatim (best measured: 187 us) =================
#define KSTR 520   // kbuf e-stride (shorts)
#define TSTR 40    // fvT/pbuf key-stride (shorts)
__global__ __launch_bounds__(256, 2) void k_flash(
    const float* __restrict__ fv, const int* __restrict__ fl,
    const short* __restrict__ wall, const int* __restrict__ wsi,
    const int* __restrict__ maxlen, float* __restrict__ part, float* __restrict__ ml,
    int* __restrict__ gcnt) {
    __shared__ short kbuf[32 * KSTR];    // [key][e] bf16
    __shared__ short fvT[512 * TSTR];    // [e][key] bf16
    __shared__ short pbuf[32 * TSTR];    // [p][key] bf16
    __shared__ float mbuf[4 * 32];
    __shared__ float lpart[4 * 32];
    __shared__ float alph[32];
    __shared__ float mrun[32];
    __shared__ float lrun[32];

    int t = threadIdx.x;
    int w = t >> 6, lane = t & 63, col = lane & 15, quad = lane >> 4;
    int b = blockIdx.x, kc = blockIdx.y;
    if (b == 0 && kc == 0 && t == 0) *gcnt = 0;   // reset k_epi's grid barrier
    int cnt = wsi[b], mlen = maxlen[0];
    int lim = cnt < mlen ? cnt : mlen;
    int off = wsi[8 + b];
    int kbase = kc * 256;
    int nv = lim - kbase; if (nv > 256) nv = 256; if (nv < 0) nv = 0;

    if (t < 32) { mrun[t] = NEGF; lrun[t] = 0.f; }

    f32x4 acc_o[2][8];
#pragma unroll
    for (int mt = 0; mt < 2; mt++)
#pragma unroll
        for (int nt = 0; nt < 8; nt++) acc_o[mt][nt] = f32x4{0.f, 0.f, 0.f, 0.f};

    const short* wallb = wall + (size_t)b * 128 * E;
    int sj = (t & 15) * 2;
    int se = (t >> 4) * 32;

    for (int s = 0; s < 8; s++) {
        int vs = nv - s * 32;
        if (vs <= 0) break;
        __syncthreads();   // protect fvT/kbuf vs previous sub-step's PV reads
        // ---- S1: stage 32 keys of fv into kbuf + fvT (bf16) ----
        {
            int g0 = off + kbase + s * 32 + sj;
            int g1 = g0 + 1;
            if (g0 > NNZ - 1) g0 = NNZ - 1;
            if (g1 > NNZ - 1) g1 = NNZ - 1;
            const float* r0 = fv + (size_t)g0 * E + se;
            const float* r1 = fv + (size_t)g1 * E + se;
#pragma unroll
            for (int i = 0; i < 8; i++) {
                float4 x0 = *(const float4*)(r0 + i * 4);
                float4 x1 = *(const float4*)(r1 + i * 4);
                int e = se + i * 4;
                *(__hip_bfloat162*)&kbuf[sj * KSTR + e]       = __float22bfloat162_rn(float2{x0.x, x0.y});
                *(__hip_bfloat162*)&kbuf[sj * KSTR + e + 2]   = __float22bfloat162_rn(float2{x0.z, x0.w});
                *(__hip_bfloat162*)&kbuf[(sj+1) * KSTR + e]   = __float22bfloat162_rn(float2{x1.x, x1.y});
                *(__hip_bfloat162*)&kbuf[(sj+1) * KSTR + e+2] = __float22bfloat162_rn(float2{x1.z, x1.w});
                *(__hip_bfloat162*)&fvT[(e + 0) * TSTR + sj] = __float22bfloat162_rn(float2{x0.x, x1.x});
                *(__hip_bfloat162*)&fvT[(e + 1) * TSTR + sj] = __float22bfloat162_rn(float2{x0.y, x1.y});
                *(__hip_bfloat162*)&fvT[(e + 2) * TSTR + sj] = __float22bfloat162_rn(float2{x0.z, x1.z});
                *(__hip_bfloat162*)&fvT[(e + 3) * TSTR + sj] = __float22bfloat162_rn(float2{x0.w, x1.w});
            }
        }
        __syncthreads();
        // ---- S2: scores MFMA: D[wall-row][key], K=512 ----
        f32x4 acc_s[2][2];
#pragma unroll
        for (int mt = 0; mt < 2; mt++)
#pragma unroll
            for (int kt = 0; kt < 2; kt++) acc_s[mt][kt] = f32x4{0.f, 0.f, 0.f, 0.f};
        {
            const short* wr0 = wallb + (size_t)(w * 32 + col) * E + quad * 8;
            const short* wr1 = wr0 + (size_t)16 * E;
            const short* kb0 = &kbuf[col * KSTR + quad * 8];
            const short* kb1 = &kbuf[(16 + col) * KSTR + quad * 8];
#pragma unroll
            for (int ks = 0; ks < 16; ks++) {
                int e0 = ks * 32;
                bf16x8 A0 = *(const bf16x8*)(wr0 + e0);
                bf16x8 A1 = *(const bf16x8*)(wr1 + e0);
                bf16x8 B0 = *(const bf16x8*)(kb0 + e0);
                bf16x8 B1 = *(const bf16x8*)(kb1 + e0);
                acc_s[0][0] = __builtin_amdgcn_mfma_f32_16x16x32_bf16(A0, B0, acc_s[0][0], 0, 0, 0);
                acc_s[0][1] = __builtin_amdgcn_mfma_f32_16x16x32_bf16(A0, B1, acc_s[0][1], 0, 0, 0);
                acc_s[1][0] = __builtin_amdgcn_mfma_f32_16x16x32_bf16(A1, B0, acc_s[1][0], 0, 0, 0);
                acc_s[1][1] = __builtin_amdgcn_mfma_f32_16x16x32_bf16(A1, B1, acc_s[1][1], 0, 0, 0);
            }
        }
        // ---- S3: per-plane sub-step max ----
        int kg0 = off + kbase + s * 32 + col;
        int kg1 = kg0 + 16;
        if (kg0 > NNZ - 1) kg0 = NNZ - 1;
        if (kg1 > NNZ - 1) kg1 = NNZ - 1;
        int lv0 = fl[kg0], lv1 = fl[kg1];
        bool valid0 = (s * 32 + col) < nv;
        bool valid1 = (s * 32 + 16 + col) < nv;
        bool sel0 = valid0 && (lv0 == w);
        bool sel1 = valid1 && (lv1 == w);
#pragma unroll
        for (int mt = 0; mt < 2; mt++) {
#pragma unroll
            for (int r = 0; r < 4; r++) {
                float v0 = sel0 ? acc_s[mt][0][r] : NEGF;
                float v1 = sel1 ? acc_s[mt][1][r] : NEGF;
                float v = fmaxf(v0, v1);
#pragma unroll
                for (int msk = 1; msk < 16; msk <<= 1) v = fmaxf(v, __shfl_xor(v, msk, 16));
                if (col == 0) mbuf[w * 32 + mt * 16 + quad * 4 + r] = v;
            }
        }
        __syncthreads();
        // ---- S4: wave0 lanes<32 update running max, compute alpha ----
        if (t < 32) {
            int p = t;
            float mo = mrun[p];
            float mn = mo;
            mn = fmaxf(mn, mbuf[p]);
            mn = fmaxf(mn, mbuf[32 + p]);
            mn = fmaxf(mn, mbuf[64 + p]);
            mn = fmaxf(mn, mbuf[96 + p]);
            alph[p] = expf(mo - mn);
            mrun[p] = mn;
        }
        __syncthreads();
        // ---- S5: P~ = exp(s - m), assemble in pbuf; partial l; rescale O ----
        float mr[2][4], ar[2][4];
#pragma unroll
        for (int mt = 0; mt < 2; mt++)
#pragma unroll
            for (int r = 0; r < 4; r++) {
                int p = mt * 16 + quad * 4 + r;
                mr[mt][r] = mrun[p];
                ar[mt][r] = alph[p];
            }
#pragma unroll
        for (int mt = 0; mt < 2; mt++) {
#pragma unroll
            for (int r = 0; r < 4; r++) {
                int p = mt * 16 + quad * 4 + r;
                float ls = 0.f;
                {
                    if (sel0) {
                        float pv = expf(acc_s[mt][0][r] - mr[mt][r]);
                        pbuf[p * TSTR + col] = f2bf(pv);
                        ls += pv;
                    } else if (w == 0 && !valid0) {
                        pbuf[p * TSTR + col] = 0;
                    }
                    if (sel1) {
                        float pv = expf(acc_s[mt][1][r] - mr[mt][r]);
                        pbuf[p * TSTR + 16 + col] = f2bf(pv);
                        ls += pv;
                    } else if (w == 0 && !valid1) {
                        pbuf[p * TSTR + 16 + col] = 0;
                    }
                }
#pragma unroll
                for (int msk = 1; msk < 16; msk <<= 1) ls += __shfl_xor(ls, msk, 16);
                if (col == 0) lpart[w * 32 + p] = ls;
            }
        }
        // rescale O accumulators by alpha
#pragma unroll
        for (int mt = 0; mt < 2; mt++)
#pragma unroll
            for (int nt = 0; nt < 8; nt++)
#pragma unroll
                for (int r = 0; r < 4; r++) acc_o[mt][nt][r] *= ar[mt][r];
        __syncthreads();
        // ---- S6: PV MFMA: O[p][e] += P~ @ fvT, K=32 keys ----
        {
            bf16x8 Ap0 = *(const bf16x8*)&pbuf[col * TSTR + quad * 8];
            bf16x8 Ap1 = *(const bf16x8*)&pbuf[(16 + col) * TSTR + quad * 8];
            const short* bt = &fvT[(size_t)(w * 128 + col) * TSTR + quad * 8];
#pragma unroll
            for (int nt = 0; nt < 8; nt++) {
                bf16x8 Bf = *(const bf16x8*)(bt + (size_t)nt * 16 * TSTR);
                acc_o[0][nt] = __builtin_amdgcn_mfma_f32_16x16x32_bf16(Ap0, Bf, acc_o[0][nt], 0, 0, 0);
                acc_o[1][nt] = __builtin_amdgcn_mfma_f32_16x16x32_bf16(Ap1, Bf, acc_o[1][nt], 0, 0, 0);
            }
        }
        // ---- S7: wave0 updates running l ----
        if (t < 32) {
            int p = t;
            lrun[p] = lrun[p] * alph[p] + (lpart[p] + lpart[32 + p] + lpart[64 + p] + lpart[96 + p]);
        }
    }
    // ---- epilogue: write partial O and (m,l) ----
    size_t pbase = ((size_t)(b * 64 + kc) * P32) * E;
#pragma unroll
    for (int mt = 0; mt < 2; mt++)
#pragma unroll
        for (int r = 0; r < 4; r++) {
            int p = mt * 16 + quad * 4 + r;
#pragma unroll
            for (int nt = 0; nt < 8; nt++) {
                int e = w * 128 + nt * 16 + col;
                part[pbase + (size_t)p * E + e] = acc_o[mt][nt][r];
            }
        }
    if (t < 32) {
        size_t idx = (size_t)(b * 64 + kc) * P32 + t;
        ml[idx * 2] = mrun[t];
        ml[idx * 2 + 1] = lrun[t];
    }
}

// ================= k_epi: merge -> oproj -> wo -> ln2 -> ffn1 -> ffn2, one kernel =================
// grid 256 x 256 thr, device-scope atomic grid barrier (all blocks co-resident: 16KB LDS).
// __threadfence() = device-scope fence; atomicAdd on global = device-scope (coherent point).
// Poll via atomicAdd(cnt,0) — a plain/volatile load could hit the stale local-XCD L2 forever.
__device__ inline void gridbar(int* cnt, int target) {
    __syncthreads();
    __threadfence();
    if (threadIdx.x == 0) {
        atomicAdd(cnt, 1);
        while (atomicAdd(cnt, 0) < target)
            __builtin_amdgcn_s_sleep(8);
    }
    __syncthreads();
    __threadfence();
}

__global__ __launch_bounds__(256) void k_epi(
    const float* __restrict__ part, const float* __restrict__ ml,
    float* __restrict__ wsum, float* __restrict__ oatt, float* __restrict__ o2,
    float* __restrict__ y, float* __restrict__ hid,
    const float* __restrict__ Wkv, const float* __restrict__ Wo,
    const float* __restrict__ bg, const float* __restrict__ lfg, const float* __restrict__ lfb,
    const float* __restrict__ W1, const float* __restrict__ b1,
    const float* __restrict__ W2, const float* __restrict__ b2,
    float* __restrict__ out, int* __restrict__ gcnt) {
    __shared__ float smem[32 * 128];   // 16 KB, reused per stage
    int bid = blockIdx.x, t = threadIdx.x;

    // ---------- stage A: merge (b = bid&7, p = bid>>3) + zero oatt ----------
    {
        if (t < 64) oatt[bid * 64 + t] = 0.f;
        int b = bid & 7, p = bid >> 3;
        float M = NEGF;
        for (int kc = 0; kc < 64; kc++)
            M = fmaxf(M, ml[((size_t)(b * 64 + kc) * P32 + p) * 2]);
        float denom = 0.f;
        for (int kc = 0; kc < 64; kc++) {
            size_t idx = ((size_t)(b * 64 + kc) * P32 + p) * 2;
            denom += ml[idx + 1] * expf(ml[idx] - M);
        }
        if (t < 64)
            smem[t] = expf(ml[((size_t)(b * 64 + t) * P32 + p) * 2] - M);
        __syncthreads();
        float inv = 1.0f / denom;
        for (int half = 0; half < 2; half++) {
            int e = t + half * 256;
            float acc = 0.f;
            for (int kc = 0; kc < 64; kc++)
                acc += part[((size_t)(b * 64 + kc) * P32 + p) * E + e] * smem[kc];
            wsum[((size_t)(b * P32 + p)) * E + e] = acc * inv;
        }
    }
    gridbar(gcnt, 256);

    // ---------- stage B: oatt += wsum_head @ Wv (split-K, 128 blocks); idle zero o2 ----------
    if (bid < 128) {
        int ct = bid & 15, kc = bid >> 4;
        int h = ct >> 1;
        {
            int rr = t >> 3, kk = (t & 7) * 8;
            int wrow = (rr >> 2) * P32 + (rr & 3) * 8 + h;
            const float* src = &wsum[(size_t)wrow * E + kc * 64 + kk];
            *(float4*)&smem[rr * 64 + kk]     = *(const float4*)src;
            *(float4*)&smem[rr * 64 + kk + 4] = *(const float4*)(src + 4);
        }
        __syncthreads();
#pragma unroll
        for (int rep = 0; rep < 4; rep++) {
            int idx = rep * 256 + t;
            int rr = idx >> 5, cl = idx & 31;
            int c = ct * 32 + cl;
            float acc = 0.f;
            const float* wp = &Wkv[(size_t)(kc * 64) * (2 * E) + E + c];
#pragma unroll
            for (int k = 0; k < 64; k++) acc += smem[rr * 64 + k] * wp[(size_t)k * (2 * E)];
            atomicAdd(&oatt[rr * E + c], acc);
        }
    } else {
        if (t < 128) o2[(bid - 128) * 128 + t] = 0.f;
    }
    gridbar(gcnt, 512);

    // ---------- stage C: o2 += oatt @ Wo (+bg on kc==0); idle zero hid ----------
    if (bid < 128) {
        int ct = bid & 15, kc = bid >> 4;
        {
            int rr = t >> 3, kk = (t & 7) * 8;
            const float* src = &oatt[(size_t)rr * E + kc * 64 + kk];
            *(float4*)&smem[rr * 64 + kk]     = *(const float4*)src;
            *(float4*)&smem[rr * 64 + kk + 4] = *(const float4*)(src + 4);
        }
        __syncthreads();
#pragma unroll
        for (int rep = 0; rep < 4; rep++) {
            int idx = rep * 256 + t;
            int rr = idx >> 5, cl = idx & 31;
            int c = ct * 32 + cl;
            float acc = (kc == 0) ? bg[rr * E + c] : 0.f;
            const float* wp = &Wo[(size_t)(kc * 64) * E + c];
#pragma unroll
            for (int k = 0; k < 64; k++) acc += smem[rr * 64 + k] * wp[(size_t)k * E];
            atomicAdd(&o2[rr * E + c], acc);
        }
    } else {
        hid[(bid - 128) * 512 + t] = 0.f;
        hid[(bid - 128) * 512 + 256 + t] = 0.f;
    }
    gridbar(gcnt, 768);

    // ---------- stage D: ln2 (32 blocks); blocks 32..159 zero out ----------
    if (bid < 32) {
        float* red = smem;
        int r = bid;
        float v0 = o2[r * E + t], v1 = o2[r * E + t + 256];
        float s = v0 + v1;
        for (int o = 32; o > 0; o >>= 1) s += __shfl_down(s, o, 64);
        if ((t & 63) == 0) red[t >> 6] = s;
        __syncthreads();
        if (t == 0) red[0] = (red[0] + red[1] + red[2] + red[3]) * (1.0f / E);
        __syncthreads();
        float mu = red[0];
        __syncthreads();
        float d0 = v0 - mu, d1 = v1 - mu;
        s = d0 * d0 + d1 * d1;
        for (int o = 32; o > 0; o >>= 1) s += __shfl_down(s, o, 64);
        if ((t & 63) == 0) red[t >> 6] = s;
        __syncthreads();
        if (t == 0) red[0] = rsqrtf((red[0] + red[1] + red[2] + red[3]) * (1.0f / E) + 1e-5f);
        __syncthreads();
        float rstd = red[0];
        y[r * E + t] = d0 * rstd * lfg[t] + lfb[t];
        y[r * E + t + 256] = d1 * rstd * lfg[t + 256] + lfb[t + 256];
    } else if (bid < 160) {
        if (t < 128) out[(bid - 32) * 128 + t] = 0.f;
    }
    gridbar(gcnt, 1024);

    // ---------- stage E: hid += y @ W1 (+b1 on kc==0), 256 blocks (64 ft x 4 kc, K=128) ----------
    {
        int ft = bid & 63, kc = bid >> 6;
        {
            int rr = t >> 3, kk = (t & 7) * 16;
            const float* src = &y[(size_t)rr * E + kc * 128 + kk];
#pragma unroll
            for (int j = 0; j < 4; j++)
                *(float4*)&smem[rr * 128 + kk + j * 4] = *(const float4*)(src + j * 4);
        }
        __syncthreads();
#pragma unroll
        for (int rep = 0; rep < 4; rep++) {
            int idx = rep * 256 + t;
            int rr = idx >> 5, fc = idx & 31;
            int f = ft * 32 + fc;
            float acc = (kc == 0) ? b1[f] : 0.f;
            const float* wp = &W1[(size_t)(kc * 128) * FFN + f];
#pragma unroll
            for (int k = 0; k < 128; k++) acc += smem[rr * 128 + k] * wp[(size_t)k * FFN];
            atomicAdd(&hid[rr * FFN + f], acc);
        }
    }
    gridbar(gcnt, 1280);

    // ---------- stage F: out += relu(hid) @ W2 (+b2+o2 on kc==0), 256 blocks (16 ct x 16 kc, K=128) ----------
    {
        int ct = bid & 15, kc = bid >> 4;
        __syncthreads();
        {
            int rr = t >> 3, kk = (t & 7) * 16;
            const float* src = &hid[(size_t)rr * FFN + kc * 128 + kk];
#pragma unroll
            for (int j = 0; j < 4; j++) {
                float4 v = *(const float4*)(src + j * 4);
                smem[rr * 128 + kk + j * 4 + 0] = fmaxf(v.x, 0.f);
                smem[rr * 128 + kk + j * 4 + 1] = fmaxf(v.y, 0.f);
                smem[rr * 128 + kk + j * 4 + 2] = fmaxf(v.z, 0.f);
                smem[rr * 128 + kk + j * 4 + 3] = fmaxf(v.w, 0.f);
            }
        }
        __syncthreads();
#pragma unroll
        for (int rep = 0; rep < 4; rep++) {
            int idx = rep * 256 + t;
            int rr = idx >> 5, cl = idx & 31;
            int c = ct * 32 + cl;
            float acc = (kc == 0) ? (b2[c] + o2[rr * E + c]) : 0.f;
            const float* wp = &W2[(size_t)(kc * 128) * E + c];
#pragma unroll
            for (int k = 0; k < 128; k++) acc += smem[rr * 128 + k] * wp[(size_t)k * E];
            atomicAdd(&out[rr * E + c], acc);
        }
    }
}

extern "C" void kernel_launch(void* const* d_in, const int* in_sizes, int n_in,
                              void* d_out, int out_size, void* d_ws, size_t ws_size,
                              hipStream_t stream) {
    const float* bg  = (const float*)d_in[0];
    const float* fv  = (const float*)d_in[1];
    const int*   fb  = (const int*)d_in[2];
    const int*   fl  = (const int*)d_in[3];
    const float* Wq  = (const float*)d_in[4];
    const float* Wkv = (const float*)d_in[5];
    const float* Wo  = (const float*)d_in[6];
    const float* rf  = (const float*)d_in[7];
    const float* lag = (const float*)d_in[8];
    const float* lab = (const float*)d_in[9];
    const float* lfg = (const float*)d_in[10];
    const float* lfb = (const float*)d_in[11];
    const float* W1  = (const float*)d_in[12];
    const float* b1  = (const float*)d_in[13];
    const float* W2  = (const float*)d_in[14];
    const float* b2  = (const float*)d_in[15];
    const int* maxlen = (const int*)d_in[16];
    float* ws = (float*)d_ws;
    int* wsi = (int*)d_ws;
    short* wall = (short*)(ws + WS_WALL);
    float* wkt = ws + WS_PART;               // WkT in (not-yet-used) part region
    int* gcnt = (int*)(ws + WS_QROT);        // grid-barrier counter (QROT region is dead otherwise)
    float* out = (float*)d_out;

    hipLaunchKernelGGL(k_pretr, dim3(65), dim3(1024), 0, stream, Wkv, wkt, fb, wsi);
    hipLaunchKernelGGL(k_qw, dim3(NQ), dim3(256), 0, stream, bg, Wq, wkt, rf, lag, lab, wall);
    hipLaunchKernelGGL(k_flash, dim3(BSZ, 64), dim3(256), 0, stream,
                       fv, fl, wall, wsi, maxlen, ws + WS_PART, ws + WS_ML, gcnt);
    hipLaunchKernelGGL(k_epi, dim3(256), dim3(256), 0, stream,
                       ws + WS_PART, ws + WS_ML, ws + WS_WSUM, ws + WS_OATT, ws + WS_O2,
                       ws + WS_Y, ws + WS_HID, Wkv, Wo, bg, lfg, lfb, W1, b1, W2, b2,
                       out, gcnt);
}